// Round 1
// baseline (1097.630 us; speedup 1.0000x reference)
//
#include <hip/hip_runtime.h>

// LaplacianBuilder: N=1024 nodes, E=16384 undirected edges, D=16 block dim.
// Output L is (N*D) x (N*D) = 16384^2 f32 = 1 GiB, block-sparse:
//   L[r,c] block = -dinv[r]*dinv[c]*(Mf^T Mt)      (r,c) edge, r<c
//   L[c,r] block = transpose of above
//   L[n,n] block = dinv[n]^2 * sum_{e: src[e]==n} M_e^T M_e
// Strategy: memset the 1 GiB (write-BW floor), then scatter the 33792
// nonzero 16x16 blocks with one workgroup per edge.

#define NN 1024
#define EE 16384
#define DD 16
#define LD (NN * DD)   // 16384 output leading dim

__global__ __launch_bounds__(256) void lap_edges_kernel(
    const float* __restrict__ maps,      // [2E][16][16]
    const float* __restrict__ degrees,   // [N]
    const int*   __restrict__ edge_index,// [2][2E]
    float* __restrict__ out)             // [16384][16384]
{
    __shared__ float Mf[256];
    __shared__ float Mt[256];

    const int e = blockIdx.x;        // 0 .. 2E-1
    const int t = threadIdx.x;       // 0 .. 255
    const int j = t >> 4;            // output row within block
    const int k = t & 15;            // output col within block

    Mf[t] = maps[(size_t)e * 256 + t];
    const int  src = edge_index[e];              // edge_index[0][e]
    const bool tri = (e < EE);
    int dst = 0;
    if (tri) {
        Mt[t] = maps[(size_t)(e + EE) * 256 + t];
        dst = edge_index[2 * EE + e];            // edge_index[1][e]
    }
    __syncthreads();

    const float dinv_s = rsqrtf(degrees[src] * 16.0f + 1.0f);

    // Diagonal contribution: B[j,k] = sum_i Mf[i,j] * Mf[i,k]
    float b = 0.0f;
    #pragma unroll
    for (int i = 0; i < 16; ++i)
        b += Mf[i * 16 + j] * Mf[i * 16 + k];
    atomicAdd(&out[(size_t)(src * 16 + j) * LD + (src * 16 + k)],
              b * dinv_s * dinv_s);

    if (tri) {
        const float dinv_d = rsqrtf(degrees[dst] * 16.0f + 1.0f);
        const float s = dinv_s * dinv_d;
        // T[j,k] = sum_i Mf[i,j]*Mt[i,k];  Tt[j,k] = T[k,j]
        float tjk = 0.0f, tkj = 0.0f;
        #pragma unroll
        for (int i = 0; i < 16; ++i) {
            const float fj = Mf[i * 16 + j];
            const float fk = Mf[i * 16 + k];
            const float gj = Mt[i * 16 + j];
            const float gk = Mt[i * 16 + k];
            tjk += fj * gk;   // T[j,k]
            tkj += fk * gj;   // T[k,j]
        }
        // L[src,dst] block, coalesced along k
        out[(size_t)(src * 16 + j) * LD + (dst * 16 + k)] = -s * tjk;
        // L[dst,src] block = -T^T, also coalesced along k
        out[(size_t)(dst * 16 + j) * LD + (src * 16 + k)] = -s * tkj;
    }
}

extern "C" void kernel_launch(void* const* d_in, const int* in_sizes, int n_in,
                              void* d_out, int out_size, void* d_ws, size_t ws_size,
                              hipStream_t stream) {
    // inputs: [0] adj_mat (unused), [1] degrees f32[N], [2] maps f32[2E*256],
    //         [3] edge_index int[2*2E]
    const float* degrees    = (const float*)d_in[1];
    const float* maps       = (const float*)d_in[2];
    const int*   edge_index = (const int*)d_in[3];
    float* out = (float*)d_out;

    // Zero the 1 GiB output (harness poisons it with 0xAA before every call).
    hipMemsetAsync(out, 0, (size_t)out_size * sizeof(float), stream);

    // One workgroup per edge (2E = 32768 blocks).
    lap_edges_kernel<<<2 * EE, 256, 0, stream>>>(maps, degrees, edge_index, out);
}